// Round 1
// baseline (1957.056 us; speedup 1.0000x reference)
//
#include <hip/hip_runtime.h>

#define IN_DIM 512
#define HID 64
#define OUT_DIM 5

__device__ __forceinline__ float fatomic_add(float* p, float v) {
    return unsafeAtomicAdd(p, v);  // hardware global_atomic_add_f32
}

// ---------------- degree / norm precompute ----------------

__global__ void k_init_deg(float* __restrict__ deg, int n) {
    int i = blockIdx.x * blockDim.x + threadIdx.x;
    if (i < n) deg[i] = 1.0f;  // self-loop weight
}

__global__ void k_accum_deg(const int* __restrict__ dst, const float* __restrict__ ew,
                            float* __restrict__ deg, int nE) {
    int e = blockIdx.x * blockDim.x + threadIdx.x;
    if (e < nE) fatomic_add(&deg[dst[e]], ew[e]);
}

__global__ void k_dinv(float* __restrict__ deg, int n) {
    int i = blockIdx.x * blockDim.x + threadIdx.x;
    if (i < n) {
        float d = deg[i];
        deg[i] = (d > 0.0f) ? (1.0f / sqrtf(d)) : 0.0f;
    }
}

__global__ void k_norm(const int* __restrict__ src, const int* __restrict__ dst,
                       const float* __restrict__ ew, const float* __restrict__ dinv,
                       float* __restrict__ norm, int nE) {
    int e = blockIdx.x * blockDim.x + threadIdx.x;
    if (e < nE) norm[e] = dinv[src[e]] * ew[e] * dinv[dst[e]];
}

// ---------------- self-loop init: out[n,:] = dinv[n]^2 * h[n,:] ----------------

__global__ void k_selfloop(const float* __restrict__ h, const float* __restrict__ dinv,
                           float* __restrict__ out, int n) {
    int t = blockIdx.x * blockDim.x + threadIdx.x;  // over n*64
    int node = t >> 6;
    if (node < n) {
        float di = dinv[node];
        out[t] = di * di * h[t];
    }
}

// ---------------- edge scatter: out[dst,:] += norm * h[src,:] ----------------
// one wave per edge: lane = feature. src/dst/norm loads are wave-uniform.

__global__ void k_scatter(const int* __restrict__ src, const int* __restrict__ dst,
                          const float* __restrict__ norm, const float* __restrict__ h,
                          float* __restrict__ out, int nE) {
    int t = blockIdx.x * blockDim.x + threadIdx.x;
    int e = t >> 6;
    int c = t & 63;
    if (e < nE) {
        int s = src[e];
        int d = dst[e];
        float w = norm[e];
        float v = h[(long long)s * HID + c];
        fatomic_add(&out[(long long)d * HID + c], w * v);
    }
}

// ---------------- tiled GEMM: out[M,64] = act(A[M,K]) @ W[K,64] ----------------
// BM=64, BN=64(all), BK=16, 256 threads, 4x4 register tile.
// RELU_BIAS: A-operand is relu(A + bias[k]) (fuses previous layer's bias+relu).

template <int K_, bool RELU_BIAS>
__launch_bounds__(256)
__global__ void k_gemm_n64(const float* __restrict__ A, const float* __restrict__ W,
                           const float* __restrict__ bias, float* __restrict__ out, int M) {
    constexpr int BK = 16;
    __shared__ float As[BK][68];   // [k][row], +4 pad keeps b128 16B-aligned, 2-way max
    __shared__ float Ws[BK][64];   // [k][col]

    const int t  = threadIdx.x;
    const int tx = t & 15;   // col group (4 cols)
    const int ty = t >> 4;   // row group (4 rows)
    const int row0 = blockIdx.x * 64;

    // staging thread mapping: 64 rows x 16 k, one float4 per thread
    const int lr = t >> 2;         // 0..63 row
    const int lk = (t & 3) * 4;    // 0,4,8,12 k-offset

    float acc[4][4] = {};

    for (int k0 = 0; k0 < K_; k0 += BK) {
        // --- A tile (transposed into LDS) ---
        float4 av = make_float4(0.f, 0.f, 0.f, 0.f);
        int ar = row0 + lr;
        if (ar < M) {
            av = *(const float4*)&A[(long long)ar * K_ + k0 + lk];
            if (RELU_BIAS) {
                const float4 bv = *(const float4*)&bias[k0 + lk];
                av.x = fmaxf(av.x + bv.x, 0.f);
                av.y = fmaxf(av.y + bv.y, 0.f);
                av.z = fmaxf(av.z + bv.z, 0.f);
                av.w = fmaxf(av.w + bv.w, 0.f);
            }
        }
        As[lk + 0][lr] = av.x;
        As[lk + 1][lr] = av.y;
        As[lk + 2][lr] = av.z;
        As[lk + 3][lr] = av.w;

        // --- W tile: 16 k-rows x 64 cols ---
        *(float4*)&Ws[t >> 4][(t & 15) * 4] =
            *(const float4*)&W[(long long)(k0 + (t >> 4)) * 64 + (t & 15) * 4];

        __syncthreads();

#pragma unroll
        for (int kk = 0; kk < BK; ++kk) {
            float4 a4 = *(const float4*)&As[kk][ty * 4];
            float4 b4 = *(const float4*)&Ws[kk][tx * 4];
            float a[4] = {a4.x, a4.y, a4.z, a4.w};
            float b[4] = {b4.x, b4.y, b4.z, b4.w};
#pragma unroll
            for (int i = 0; i < 4; ++i)
#pragma unroll
                for (int j = 0; j < 4; ++j)
                    acc[i][j] = fmaf(a[i], b[j], acc[i][j]);
        }
        __syncthreads();
    }

#pragma unroll
    for (int i = 0; i < 4; ++i) {
        int r = row0 + ty * 4 + i;
        if (r < M) {
            *(float4*)&out[(long long)r * 64 + tx * 4] =
                make_float4(acc[i][0], acc[i][1], acc[i][2], acc[i][3]);
        }
    }
}

// ---------------- final: out[n,:5] = relu(agg[n,:]+b2) @ Wfc + bfc ----------------

__launch_bounds__(256)
__global__ void k_final(const float* __restrict__ agg, const float* __restrict__ b2,
                        const float* __restrict__ Wfc, const float* __restrict__ bfc,
                        float* __restrict__ out, int N) {
    __shared__ float Wsf[HID * OUT_DIM];  // 320
    __shared__ float bs[HID];
    int t = threadIdx.x;
    for (int i = t; i < HID * OUT_DIM; i += 256) Wsf[i] = Wfc[i];
    if (t < HID) bs[t] = b2[t];
    __syncthreads();

    int n = blockIdx.x * blockDim.x + t;
    if (n >= N) return;

    float acc[OUT_DIM];
#pragma unroll
    for (int o = 0; o < OUT_DIM; ++o) acc[o] = bfc[o];

    const float4* ag = (const float4*)&agg[(long long)n * HID];
#pragma unroll
    for (int k4 = 0; k4 < HID / 4; ++k4) {
        float4 v4 = ag[k4];
        float v[4] = {v4.x, v4.y, v4.z, v4.w};
#pragma unroll
        for (int j = 0; j < 4; ++j) {
            int k = k4 * 4 + j;
            float f = fmaxf(v[j] + bs[k], 0.f);
#pragma unroll
            for (int o = 0; o < OUT_DIM; ++o)
                acc[o] = fmaf(f, Wsf[k * OUT_DIM + o], acc[o]);
        }
    }
#pragma unroll
    for (int o = 0; o < OUT_DIM; ++o) out[(long long)n * OUT_DIM + o] = acc[o];
}

// ---------------- host launch ----------------

static inline size_t align_up(size_t x, size_t a) { return (x + a - 1) & ~(a - 1); }

extern "C" void kernel_launch(void* const* d_in, const int* in_sizes, int n_in,
                              void* d_out, int out_size, void* d_ws, size_t ws_size,
                              hipStream_t stream) {
    const float* x   = (const float*)d_in[0];
    const int*   ei  = (const int*)d_in[1];   // [2][E] int32 (per harness convention)
    const float* ew  = (const float*)d_in[2];
    const float* W1  = (const float*)d_in[3];
    const float* b1  = (const float*)d_in[4];
    const float* W2  = (const float*)d_in[5];
    const float* b2  = (const float*)d_in[6];
    const float* Wfc = (const float*)d_in[7];
    const float* bfc = (const float*)d_in[8];
    float* out = (float*)d_out;

    const int E = in_sizes[2];              // 3200000
    const int N = in_sizes[0] / IN_DIM;     // 100000
    const int* src = ei;
    const int* dst = ei + E;

    // workspace carve
    char* p = (char*)d_ws;
    float* dinv = (float*)p;                 p += align_up((size_t)N * 4, 256);
    float* norm = (float*)p;                 p += align_up((size_t)E * 4, 256);
    float* bufA = (float*)p;                 p += align_up((size_t)N * HID * 4, 256);
    float* bufB = (float*)p;                 p += align_up((size_t)N * HID * 4, 256);
    float* bufC = (float*)p;                 p += align_up((size_t)N * HID * 4, 256);
    (void)ws_size; (void)n_in; (void)out_size;

    const int BS = 256;
    dim3 blk(BS);
    int gN   = (N + BS - 1) / BS;
    int gE   = (E + BS - 1) / BS;
    int gNH  = (N * HID + BS - 1) / BS;
    long long scatter_threads = (long long)E * 64;
    int gSC  = (int)((scatter_threads + BS - 1) / BS);
    int gM   = (N + 63) / 64;

    // norm precompute
    k_init_deg<<<gN, blk, 0, stream>>>(dinv, N);
    k_accum_deg<<<gE, blk, 0, stream>>>(dst, ew, dinv, E);
    k_dinv<<<gN, blk, 0, stream>>>(dinv, N);
    k_norm<<<gE, blk, 0, stream>>>(src, dst, ew, dinv, norm, E);

    // layer 1: h1 = x @ W1 ; agg1 = selfloop + scatter
    k_gemm_n64<IN_DIM, false><<<gM, blk, 0, stream>>>(x, W1, nullptr, bufA, N);
    k_selfloop<<<gNH, blk, 0, stream>>>(bufA, dinv, bufB, N);
    k_scatter<<<gSC, blk, 0, stream>>>(src, dst, norm, bufA, bufB, E);

    // layer 2: h2 = relu(agg1 + b1) @ W2 ; agg2 = selfloop + scatter
    k_gemm_n64<HID, true><<<gM, blk, 0, stream>>>(bufB, W2, b1, bufC, N);
    k_selfloop<<<gNH, blk, 0, stream>>>(bufC, dinv, bufA, N);
    k_scatter<<<gSC, blk, 0, stream>>>(src, dst, norm, bufC, bufA, E);

    // final FC with fused relu+b2
    k_final<<<gN, blk, 0, stream>>>(bufA, b2, Wfc, bfc, out, N);
}

// Round 2
// 1040.865 us; speedup vs baseline: 1.8802x; 1.8802x over previous
//
#include <hip/hip_runtime.h>

#define IN_DIM 512
#define HID 64
#define OUT_DIM 5

__device__ __forceinline__ float fatomic_add(float* p, float v) {
    return unsafeAtomicAdd(p, v);  // hardware global_atomic_add_f32
}

// ---------------- init: deg=1 (self loop), counts=0 ----------------

__global__ void k_init(float* __restrict__ deg, int* __restrict__ cnt, int n) {
    int i = blockIdx.x * blockDim.x + threadIdx.x;
    if (i < n) { deg[i] = 1.0f; cnt[i] = 0; }
}

// ---------------- fused: deg[dst] += ew (fp atomic) ; cnt[dst]++ (int atomic) ----------------

__global__ void k_deg_hist(const int* __restrict__ dst, const float* __restrict__ ew,
                           float* __restrict__ deg, int* __restrict__ cnt, int nE) {
    int e = blockIdx.x * blockDim.x + threadIdx.x;
    if (e < nE) {
        int d = dst[e];
        fatomic_add(&deg[d], ew[e]);
        atomicAdd(&cnt[d], 1);
    }
}

__global__ void k_dinv(float* __restrict__ deg, int n) {
    int i = blockIdx.x * blockDim.x + threadIdx.x;
    if (i < n) {
        float d = deg[i];
        deg[i] = (d > 0.0f) ? (1.0f / sqrtf(d)) : 0.0f;
    }
}

// ---------------- exclusive scan of cnt -> rowptr (3-kernel hierarchical) ----------------
// scan1: each 256-thread block scans 1024 counts, emits block sum.

__global__ void k_scan1(const int* __restrict__ cnt, int* __restrict__ rowptr,
                        int* __restrict__ bsum, int n) {
    __shared__ int sdata[256];
    int t = threadIdx.x, b = blockIdx.x;
    int base = b * 1024 + t * 4;
    int v[4], s = 0;
#pragma unroll
    for (int k = 0; k < 4; ++k) { int i = base + k; v[k] = (i < n) ? cnt[i] : 0; s += v[k]; }
    sdata[t] = s;
    __syncthreads();
    int x = s;
    for (int off = 1; off < 256; off <<= 1) {
        int y = (t >= off) ? sdata[t - off] : 0;
        __syncthreads();
        x += y;
        sdata[t] = x;
        __syncthreads();
    }
    int run = x - s;  // exclusive prefix of this thread's group
    if (t == 255) bsum[b] = x;  // block total (inclusive of all 1024)
#pragma unroll
    for (int k = 0; k < 4; ++k) { int i = base + k; if (i < n) rowptr[i] = run; run += v[k]; }
}

// scan2: single block exclusive-scans the block sums in place (nb <= 256).

__global__ void k_scan2(int* __restrict__ bsum, int nb) {
    __shared__ int sdata[256];
    int t = threadIdx.x;
    int s = (t < nb) ? bsum[t] : 0;
    sdata[t] = s;
    __syncthreads();
    int x = s;
    for (int off = 1; off < 256; off <<= 1) {
        int y = (t >= off) ? sdata[t - off] : 0;
        __syncthreads();
        x += y;
        sdata[t] = x;
        __syncthreads();
    }
    if (t < nb) bsum[t] = x - s;  // exclusive
}

// scan3: add block offsets, mirror into cursor, set rowptr[n]=E.

__global__ void k_scan3(int* __restrict__ rowptr, int* __restrict__ cursor,
                        const int* __restrict__ bsum, int n, int E) {
    int i = blockIdx.x * blockDim.x + threadIdx.x;
    if (i < n) {
        int r = rowptr[i] + bsum[i >> 10];
        rowptr[i] = r;
        cursor[i] = r;
    } else if (i == n) {
        rowptr[n] = E;
    }
}

// ---------------- reorder: payload[pos] = (src, norm) sorted by dst ----------------

__global__ void k_reorder(const int* __restrict__ src, const int* __restrict__ dst,
                          const float* __restrict__ ew, const float* __restrict__ dinv,
                          int* __restrict__ cursor, int2* __restrict__ edges, int nE) {
    int e = blockIdx.x * blockDim.x + threadIdx.x;
    if (e < nE) {
        int s = src[e];
        int d = dst[e];
        float w = dinv[s] * ew[e] * dinv[d];
        int pos = atomicAdd(&cursor[d], 1);
        edges[pos] = make_int2(s, __float_as_int(w));
    }
}

// ---------------- aggregate: out[n,:] = dinv[n]^2*h[n,:] + sum_e w_e * h[src_e,:] ----------------
// one wave per node, lane = feature. No atomics.

__launch_bounds__(256)
__global__ void k_aggregate(const float* __restrict__ h, const float* __restrict__ dinv,
                            const int2* __restrict__ edges, const int* __restrict__ rowptr,
                            float* __restrict__ out, int N) {
    int n = (blockIdx.x * 256 + threadIdx.x) >> 6;
    int lane = threadIdx.x & 63;
    if (n >= N) return;

    float dn = dinv[n];
    float acc = dn * dn * h[(size_t)n * HID + lane];

    int beg = rowptr[n], end = rowptr[n + 1];
    int j = beg;
    for (; j + 3 < end; j += 4) {
        int2 p0 = edges[j];
        int2 p1 = edges[j + 1];
        int2 p2 = edges[j + 2];
        int2 p3 = edges[j + 3];
        float h0 = h[(size_t)p0.x * HID + lane];
        float h1 = h[(size_t)p1.x * HID + lane];
        float h2 = h[(size_t)p2.x * HID + lane];
        float h3 = h[(size_t)p3.x * HID + lane];
        acc = fmaf(__int_as_float(p0.y), h0, acc);
        acc = fmaf(__int_as_float(p1.y), h1, acc);
        acc = fmaf(__int_as_float(p2.y), h2, acc);
        acc = fmaf(__int_as_float(p3.y), h3, acc);
    }
    for (; j < end; ++j) {
        int2 p = edges[j];
        acc = fmaf(__int_as_float(p.y), h[(size_t)p.x * HID + lane], acc);
    }
    out[(size_t)n * HID + lane] = acc;
}

// ---------------- tiled GEMM: out[M,64] = act(A[M,K]) @ W[K,64] ----------------

template <int K_, bool RELU_BIAS>
__launch_bounds__(256)
__global__ void k_gemm_n64(const float* __restrict__ A, const float* __restrict__ W,
                           const float* __restrict__ bias, float* __restrict__ out, int M) {
    constexpr int BK = 16;
    __shared__ float As[BK][68];
    __shared__ float Ws[BK][64];

    const int t  = threadIdx.x;
    const int tx = t & 15;
    const int ty = t >> 4;
    const int row0 = blockIdx.x * 64;

    const int lr = t >> 2;
    const int lk = (t & 3) * 4;

    float acc[4][4] = {};

    for (int k0 = 0; k0 < K_; k0 += BK) {
        float4 av = make_float4(0.f, 0.f, 0.f, 0.f);
        int ar = row0 + lr;
        if (ar < M) {
            av = *(const float4*)&A[(long long)ar * K_ + k0 + lk];
            if (RELU_BIAS) {
                const float4 bv = *(const float4*)&bias[k0 + lk];
                av.x = fmaxf(av.x + bv.x, 0.f);
                av.y = fmaxf(av.y + bv.y, 0.f);
                av.z = fmaxf(av.z + bv.z, 0.f);
                av.w = fmaxf(av.w + bv.w, 0.f);
            }
        }
        As[lk + 0][lr] = av.x;
        As[lk + 1][lr] = av.y;
        As[lk + 2][lr] = av.z;
        As[lk + 3][lr] = av.w;

        *(float4*)&Ws[t >> 4][(t & 15) * 4] =
            *(const float4*)&W[(long long)(k0 + (t >> 4)) * 64 + (t & 15) * 4];

        __syncthreads();

#pragma unroll
        for (int kk = 0; kk < BK; ++kk) {
            float4 a4 = *(const float4*)&As[kk][ty * 4];
            float4 b4 = *(const float4*)&Ws[kk][tx * 4];
            float a[4] = {a4.x, a4.y, a4.z, a4.w};
            float b[4] = {b4.x, b4.y, b4.z, b4.w};
#pragma unroll
            for (int i = 0; i < 4; ++i)
#pragma unroll
                for (int j = 0; j < 4; ++j)
                    acc[i][j] = fmaf(a[i], b[j], acc[i][j]);
        }
        __syncthreads();
    }

#pragma unroll
    for (int i = 0; i < 4; ++i) {
        int r = row0 + ty * 4 + i;
        if (r < M) {
            *(float4*)&out[(long long)r * 64 + tx * 4] =
                make_float4(acc[i][0], acc[i][1], acc[i][2], acc[i][3]);
        }
    }
}

// ---------------- final: out[n,:5] = relu(agg[n,:]+b2) @ Wfc + bfc ----------------

__launch_bounds__(256)
__global__ void k_final(const float* __restrict__ agg, const float* __restrict__ b2,
                        const float* __restrict__ Wfc, const float* __restrict__ bfc,
                        float* __restrict__ out, int N) {
    __shared__ float Wsf[HID * OUT_DIM];
    __shared__ float bs[HID];
    int t = threadIdx.x;
    for (int i = t; i < HID * OUT_DIM; i += 256) Wsf[i] = Wfc[i];
    if (t < HID) bs[t] = b2[t];
    __syncthreads();

    int n = blockIdx.x * blockDim.x + t;
    if (n >= N) return;

    float acc[OUT_DIM];
#pragma unroll
    for (int o = 0; o < OUT_DIM; ++o) acc[o] = bfc[o];

    const float4* ag = (const float4*)&agg[(long long)n * HID];
#pragma unroll
    for (int k4 = 0; k4 < HID / 4; ++k4) {
        float4 v4 = ag[k4];
        float v[4] = {v4.x, v4.y, v4.z, v4.w};
#pragma unroll
        for (int j = 0; j < 4; ++j) {
            int k = k4 * 4 + j;
            float f = fmaxf(v[j] + bs[k], 0.f);
#pragma unroll
            for (int o = 0; o < OUT_DIM; ++o)
                acc[o] = fmaf(f, Wsf[k * OUT_DIM + o], acc[o]);
        }
    }
#pragma unroll
    for (int o = 0; o < OUT_DIM; ++o) out[(long long)n * OUT_DIM + o] = acc[o];
}

// ---------------- host launch ----------------

static inline size_t align_up(size_t x, size_t a) { return (x + a - 1) & ~(a - 1); }

extern "C" void kernel_launch(void* const* d_in, const int* in_sizes, int n_in,
                              void* d_out, int out_size, void* d_ws, size_t ws_size,
                              hipStream_t stream) {
    const float* x   = (const float*)d_in[0];
    const int*   ei  = (const int*)d_in[1];   // [2][E] int32
    const float* ew  = (const float*)d_in[2];
    const float* W1  = (const float*)d_in[3];
    const float* b1  = (const float*)d_in[4];
    const float* W2  = (const float*)d_in[5];
    const float* b2  = (const float*)d_in[6];
    const float* Wfc = (const float*)d_in[7];
    const float* bfc = (const float*)d_in[8];
    float* out = (float*)d_out;

    const int E = in_sizes[2];              // 3200000
    const int N = in_sizes[0] / IN_DIM;     // 100000
    const int* src = ei;
    const int* dst = ei + E;

    // workspace carve
    char* p = (char*)d_ws;
    float* dinv   = (float*)p;  p += align_up((size_t)N * 4, 256);
    int*   cursor = (int*)p;    p += align_up((size_t)N * 4, 256);
    int*   rowptr = (int*)p;    p += align_up((size_t)(N + 1) * 4, 256);
    int*   bsum   = (int*)p;    p += align_up((size_t)256 * 4, 256);
    int2*  edges  = (int2*)p;   p += align_up((size_t)E * 8, 256);
    float* bufA   = (float*)p;  p += align_up((size_t)N * HID * 4, 256);
    float* bufB   = (float*)p;  p += align_up((size_t)N * HID * 4, 256);
    (void)ws_size; (void)n_in; (void)out_size;

    const int BS = 256;
    dim3 blk(BS);
    int gN  = (N + BS - 1) / BS;
    int gN1 = (N + 1 + BS - 1) / BS;
    int gE  = (E + BS - 1) / BS;
    int gM  = (N + 63) / 64;
    int nb  = (N + 1023) / 1024;            // scan1 blocks (<=256)
    int gAg = (N + 3) / 4;                  // 4 waves/block, 1 node/wave

    // degree + histogram (independent accumulations, fused pass over dst)
    k_init<<<gN, blk, 0, stream>>>(dinv, cursor, N);
    k_deg_hist<<<gE, blk, 0, stream>>>(dst, ew, dinv, cursor, E);
    k_dinv<<<gN, blk, 0, stream>>>(dinv, N);

    // exclusive scan cnt -> rowptr; cursor := rowptr
    k_scan1<<<nb, blk, 0, stream>>>(cursor, rowptr, bsum, N);
    k_scan2<<<1, blk, 0, stream>>>(bsum, nb);
    k_scan3<<<gN1, blk, 0, stream>>>(rowptr, cursor, bsum, N, E);

    // dst-sorted edge payload (src, norm)
    k_reorder<<<gE, blk, 0, stream>>>(src, dst, ew, dinv, cursor, edges, E);

    // layer 1
    k_gemm_n64<IN_DIM, false><<<gM, blk, 0, stream>>>(x, W1, nullptr, bufA, N);
    k_aggregate<<<gAg, blk, 0, stream>>>(bufA, dinv, edges, rowptr, bufB, N);

    // layer 2
    k_gemm_n64<HID, true><<<gM, blk, 0, stream>>>(bufB, W2, b1, bufA, N);
    k_aggregate<<<gAg, blk, 0, stream>>>(bufA, dinv, edges, rowptr, bufB, N);

    // final FC
    k_final<<<gN, blk, 0, stream>>>(bufB, b2, Wfc, bfc, out, N);
}

// Round 3
// 868.110 us; speedup vs baseline: 2.2544x; 1.1990x over previous
//
#include <hip/hip_runtime.h>

#define IN_DIM 512
#define HID 64
#define OUT_DIM 5

// ---------------- init: packed deg/count accumulator = 0 ----------------

__global__ void k_init(unsigned long long* __restrict__ packed, int n) {
    int i = blockIdx.x * blockDim.x + threadIdx.x;
    if (i < n) packed[i] = 0ULL;
}

// ---------------- hist: ONE packed 64-bit atomic per edge ----------------
// packed[d] layout: bits [63:44] = incoming-edge count, bits [43:0] = sum(ew) in 12.32 fixed pt.
// atomic return gives this edge's rank within its dst bucket for free.

__global__ void k_hist(const int* __restrict__ dst, const float* __restrict__ ew,
                       unsigned long long* __restrict__ packed, int* __restrict__ rank, int nE) {
    int e = blockIdx.x * blockDim.x + threadIdx.x;
    if (e < nE) {
        int d = dst[e];
        unsigned long long fx = (unsigned long long)(ew[e] * 4294967296.0);  // < 2^32
        unsigned long long old = atomicAdd(&packed[d], (1ULL << 44) | fx);
        rank[e] = (int)(old >> 44);
    }
}

// ---------------- unpack: dinv = rsqrt(1 + sum_ew), cnt for scan ----------------

__global__ void k_dinv(const unsigned long long* __restrict__ packed,
                       float* __restrict__ dinv, int* __restrict__ cnt, int n) {
    int i = blockIdx.x * blockDim.x + threadIdx.x;
    if (i < n) {
        unsigned long long p = packed[i];
        int c = (int)(p >> 44);
        double ewsum = (double)(p & ((1ULL << 44) - 1)) * (1.0 / 4294967296.0);
        float deg = 1.0f + (float)ewsum;  // self-loop weight 1 => deg >= 1 always
        dinv[i] = rsqrtf(deg);
        cnt[i] = c;
    }
}

// ---------------- exclusive scan of cnt -> rowptr (3-kernel hierarchical) ----------------

__global__ void k_scan1(const int* __restrict__ cnt, int* __restrict__ rowptr,
                        int* __restrict__ bsum, int n) {
    __shared__ int sdata[256];
    int t = threadIdx.x, b = blockIdx.x;
    int base = b * 1024 + t * 4;
    int v[4], s = 0;
#pragma unroll
    for (int k = 0; k < 4; ++k) { int i = base + k; v[k] = (i < n) ? cnt[i] : 0; s += v[k]; }
    sdata[t] = s;
    __syncthreads();
    int x = s;
    for (int off = 1; off < 256; off <<= 1) {
        int y = (t >= off) ? sdata[t - off] : 0;
        __syncthreads();
        x += y;
        sdata[t] = x;
        __syncthreads();
    }
    int run = x - s;
    if (t == 255) bsum[b] = x;
#pragma unroll
    for (int k = 0; k < 4; ++k) { int i = base + k; if (i < n) rowptr[i] = run; run += v[k]; }
}

__global__ void k_scan2(int* __restrict__ bsum, int nb) {
    __shared__ int sdata[256];
    int t = threadIdx.x;
    int s = (t < nb) ? bsum[t] : 0;
    sdata[t] = s;
    __syncthreads();
    int x = s;
    for (int off = 1; off < 256; off <<= 1) {
        int y = (t >= off) ? sdata[t - off] : 0;
        __syncthreads();
        x += y;
        sdata[t] = x;
        __syncthreads();
    }
    if (t < nb) bsum[t] = x - s;
}

__global__ void k_scan3(int* __restrict__ rowptr, const int* __restrict__ bsum, int n, int E) {
    int i = blockIdx.x * blockDim.x + threadIdx.x;
    if (i < n) rowptr[i] += bsum[i >> 10];
    else if (i == n) rowptr[n] = E;
}

// ---------------- reorder: NO atomics — pos = rowptr[dst] + rank ----------------

__global__ void k_reorder(const int* __restrict__ src, const int* __restrict__ dst,
                          const float* __restrict__ ew, const float* __restrict__ dinv,
                          const int* __restrict__ rowptr, const int* __restrict__ rank,
                          int2* __restrict__ edges, int nE) {
    int e = blockIdx.x * blockDim.x + threadIdx.x;
    if (e < nE) {
        int s = src[e];
        int d = dst[e];
        float w = dinv[s] * ew[e] * dinv[d];
        int pos = rowptr[d] + rank[e];
        edges[pos] = make_int2(s, __float_as_int(w));
    }
}

// ---------------- aggregate: out[n,:] = dinv[n]^2*h[n,:] + sum_e w_e * h[src_e,:] ----------------
// one wave per node, lane = feature. No atomics.

__launch_bounds__(256)
__global__ void k_aggregate(const float* __restrict__ h, const float* __restrict__ dinv,
                            const int2* __restrict__ edges, const int* __restrict__ rowptr,
                            float* __restrict__ out, int N) {
    int n = (blockIdx.x * 256 + threadIdx.x) >> 6;
    int lane = threadIdx.x & 63;
    if (n >= N) return;

    float dn = dinv[n];
    float acc = dn * dn * h[(size_t)n * HID + lane];

    int beg = rowptr[n], end = rowptr[n + 1];
    int j = beg;
    for (; j + 3 < end; j += 4) {
        int2 p0 = edges[j];
        int2 p1 = edges[j + 1];
        int2 p2 = edges[j + 2];
        int2 p3 = edges[j + 3];
        float h0 = h[(size_t)p0.x * HID + lane];
        float h1 = h[(size_t)p1.x * HID + lane];
        float h2 = h[(size_t)p2.x * HID + lane];
        float h3 = h[(size_t)p3.x * HID + lane];
        acc = fmaf(__int_as_float(p0.y), h0, acc);
        acc = fmaf(__int_as_float(p1.y), h1, acc);
        acc = fmaf(__int_as_float(p2.y), h2, acc);
        acc = fmaf(__int_as_float(p3.y), h3, acc);
    }
    for (; j < end; ++j) {
        int2 p = edges[j];
        acc = fmaf(__int_as_float(p.y), h[(size_t)p.x * HID + lane], acc);
    }
    out[(size_t)n * HID + lane] = acc;
}

// ---------------- tiled GEMM: out[M,64] = act(A[M,K]) @ W[K,64] ----------------

template <int K_, bool RELU_BIAS>
__launch_bounds__(256)
__global__ void k_gemm_n64(const float* __restrict__ A, const float* __restrict__ W,
                           const float* __restrict__ bias, float* __restrict__ out, int M) {
    constexpr int BK = 16;
    __shared__ float As[BK][68];
    __shared__ float Ws[BK][64];

    const int t  = threadIdx.x;
    const int tx = t & 15;
    const int ty = t >> 4;
    const int row0 = blockIdx.x * 64;

    const int lr = t >> 2;
    const int lk = (t & 3) * 4;

    float acc[4][4] = {};

    for (int k0 = 0; k0 < K_; k0 += BK) {
        float4 av = make_float4(0.f, 0.f, 0.f, 0.f);
        int ar = row0 + lr;
        if (ar < M) {
            av = *(const float4*)&A[(long long)ar * K_ + k0 + lk];
            if (RELU_BIAS) {
                const float4 bv = *(const float4*)&bias[k0 + lk];
                av.x = fmaxf(av.x + bv.x, 0.f);
                av.y = fmaxf(av.y + bv.y, 0.f);
                av.z = fmaxf(av.z + bv.z, 0.f);
                av.w = fmaxf(av.w + bv.w, 0.f);
            }
        }
        As[lk + 0][lr] = av.x;
        As[lk + 1][lr] = av.y;
        As[lk + 2][lr] = av.z;
        As[lk + 3][lr] = av.w;

        *(float4*)&Ws[t >> 4][(t & 15) * 4] =
            *(const float4*)&W[(long long)(k0 + (t >> 4)) * 64 + (t & 15) * 4];

        __syncthreads();

#pragma unroll
        for (int kk = 0; kk < BK; ++kk) {
            float4 a4 = *(const float4*)&As[kk][ty * 4];
            float4 b4 = *(const float4*)&Ws[kk][tx * 4];
            float a[4] = {a4.x, a4.y, a4.z, a4.w};
            float b[4] = {b4.x, b4.y, b4.z, b4.w};
#pragma unroll
            for (int i = 0; i < 4; ++i)
#pragma unroll
                for (int j = 0; j < 4; ++j)
                    acc[i][j] = fmaf(a[i], b[j], acc[i][j]);
        }
        __syncthreads();
    }

#pragma unroll
    for (int i = 0; i < 4; ++i) {
        int r = row0 + ty * 4 + i;
        if (r < M) {
            *(float4*)&out[(long long)r * 64 + tx * 4] =
                make_float4(acc[i][0], acc[i][1], acc[i][2], acc[i][3]);
        }
    }
}

// ---------------- final: out[n,:5] = relu(agg[n,:]+b2) @ Wfc + bfc ----------------

__launch_bounds__(256)
__global__ void k_final(const float* __restrict__ agg, const float* __restrict__ b2,
                        const float* __restrict__ Wfc, const float* __restrict__ bfc,
                        float* __restrict__ out, int N) {
    __shared__ float Wsf[HID * OUT_DIM];
    __shared__ float bs[HID];
    int t = threadIdx.x;
    for (int i = t; i < HID * OUT_DIM; i += 256) Wsf[i] = Wfc[i];
    if (t < HID) bs[t] = b2[t];
    __syncthreads();

    int n = blockIdx.x * blockDim.x + t;
    if (n >= N) return;

    float acc[OUT_DIM];
#pragma unroll
    for (int o = 0; o < OUT_DIM; ++o) acc[o] = bfc[o];

    const float4* ag = (const float4*)&agg[(long long)n * HID];
#pragma unroll
    for (int k4 = 0; k4 < HID / 4; ++k4) {
        float4 v4 = ag[k4];
        float v[4] = {v4.x, v4.y, v4.z, v4.w};
#pragma unroll
        for (int j = 0; j < 4; ++j) {
            int k = k4 * 4 + j;
            float f = fmaxf(v[j] + bs[k], 0.f);
#pragma unroll
            for (int o = 0; o < OUT_DIM; ++o)
                acc[o] = fmaf(f, Wsf[k * OUT_DIM + o], acc[o]);
        }
    }
#pragma unroll
    for (int o = 0; o < OUT_DIM; ++o) out[(long long)n * OUT_DIM + o] = acc[o];
}

// ---------------- host launch ----------------

static inline size_t align_up(size_t x, size_t a) { return (x + a - 1) & ~(a - 1); }

extern "C" void kernel_launch(void* const* d_in, const int* in_sizes, int n_in,
                              void* d_out, int out_size, void* d_ws, size_t ws_size,
                              hipStream_t stream) {
    const float* x   = (const float*)d_in[0];
    const int*   ei  = (const int*)d_in[1];   // [2][E] int32
    const float* ew  = (const float*)d_in[2];
    const float* W1  = (const float*)d_in[3];
    const float* b1  = (const float*)d_in[4];
    const float* W2  = (const float*)d_in[5];
    const float* b2  = (const float*)d_in[6];
    const float* Wfc = (const float*)d_in[7];
    const float* bfc = (const float*)d_in[8];
    float* out = (float*)d_out;

    const int E = in_sizes[2];              // 3200000
    const int N = in_sizes[0] / IN_DIM;     // 100000
    const int* src = ei;
    const int* dst = ei + E;

    // workspace carve
    char* p = (char*)d_ws;
    unsigned long long* packed = (unsigned long long*)p; p += align_up((size_t)N * 8, 256);
    float* dinv   = (float*)p;  p += align_up((size_t)N * 4, 256);
    int*   cnt    = (int*)p;    p += align_up((size_t)N * 4, 256);
    int*   rowptr = (int*)p;    p += align_up((size_t)(N + 1) * 4, 256);
    int*   bsum   = (int*)p;    p += align_up((size_t)256 * 4, 256);
    int*   rank   = (int*)p;    p += align_up((size_t)E * 4, 256);
    int2*  edges  = (int2*)p;   p += align_up((size_t)E * 8, 256);
    float* bufA   = (float*)p;  p += align_up((size_t)N * HID * 4, 256);
    float* bufB   = (float*)p;  p += align_up((size_t)N * HID * 4, 256);
    (void)ws_size; (void)n_in; (void)out_size;

    const int BS = 256;
    dim3 blk(BS);
    int gN  = (N + BS - 1) / BS;
    int gN1 = (N + 1 + BS - 1) / BS;
    int gE  = (E + BS - 1) / BS;
    int gM  = (N + 63) / 64;
    int nb  = (N + 1023) / 1024;
    int gAg = (N + 3) / 4;

    // CSR build: 1 scattered atomic per edge total
    k_init<<<gN, blk, 0, stream>>>(packed, N);
    k_hist<<<gE, blk, 0, stream>>>(dst, ew, packed, rank, E);
    k_dinv<<<gN, blk, 0, stream>>>(packed, dinv, cnt, N);
    k_scan1<<<nb, blk, 0, stream>>>(cnt, rowptr, bsum, N);
    k_scan2<<<1, blk, 0, stream>>>(bsum, nb);
    k_scan3<<<gN1, blk, 0, stream>>>(rowptr, bsum, N, E);
    k_reorder<<<gE, blk, 0, stream>>>(src, dst, ew, dinv, rowptr, rank, edges, E);

    // layer 1
    k_gemm_n64<IN_DIM, false><<<gM, blk, 0, stream>>>(x, W1, nullptr, bufA, N);
    k_aggregate<<<gAg, blk, 0, stream>>>(bufA, dinv, edges, rowptr, bufB, N);

    // layer 2
    k_gemm_n64<HID, true><<<gM, blk, 0, stream>>>(bufB, W2, b1, bufA, N);
    k_aggregate<<<gAg, blk, 0, stream>>>(bufA, dinv, edges, rowptr, bufB, N);

    // final FC
    k_final<<<gN, blk, 0, stream>>>(bufB, b2, Wfc, bfc, out, N);
}

// Round 5
// 856.120 us; speedup vs baseline: 2.2860x; 1.0140x over previous
//
#include <hip/hip_runtime.h>

#define IN_DIM 512
#define HID 64
#define OUT_DIM 5

// ---------------- bf16 helpers (RNE) ----------------

__device__ __forceinline__ unsigned short f2bf(float f) {
    unsigned u = __float_as_uint(f);
    u += 0x7FFF + ((u >> 16) & 1);
    return (unsigned short)(u >> 16);
}
__device__ __forceinline__ float bf2f(unsigned short b) {
    return __uint_as_float(((unsigned)b) << 16);
}

// ---------------- init: packed deg/count accumulator = 0 ----------------

__global__ void k_init(unsigned long long* __restrict__ packed, int n) {
    int i = blockIdx.x * blockDim.x + threadIdx.x;
    if (i < n) packed[i] = 0ULL;
}

// ---------------- hist: ONE packed 64-bit atomic per edge ----------------
// packed[d]: bits [63:44] = incoming-edge count, [43:0] = sum(ew) in 12.32 fixed pt.
// atomic return gives this edge's rank within its dst bucket for free.

__global__ void k_hist(const int* __restrict__ dst, const float* __restrict__ ew,
                       unsigned long long* __restrict__ packed, int* __restrict__ rank, int nE) {
    int e = blockIdx.x * blockDim.x + threadIdx.x;
    if (e < nE) {
        int d = dst[e];
        unsigned long long fx = (unsigned long long)(ew[e] * 4294967296.0);  // < 2^32
        unsigned long long old = atomicAdd(&packed[d], (1ULL << 44) | fx);
        rank[e] = (int)(old >> 44);
    }
}

// ---------------- unpack: dinv = rsqrt(1 + sum_ew), cnt for scan ----------------

__global__ void k_dinv(const unsigned long long* __restrict__ packed,
                       float* __restrict__ dinv, int* __restrict__ cnt, int n) {
    int i = blockIdx.x * blockDim.x + threadIdx.x;
    if (i < n) {
        unsigned long long p = packed[i];
        int c = (int)(p >> 44);
        double ewsum = (double)(p & ((1ULL << 44) - 1)) * (1.0 / 4294967296.0);
        float deg = 1.0f + (float)ewsum;  // self-loop weight 1 => deg >= 1 always
        dinv[i] = rsqrtf(deg);
        cnt[i] = c;
    }
}

// ---------------- exclusive scan of cnt -> rowptr (3-kernel hierarchical) ----------------

__global__ void k_scan1(const int* __restrict__ cnt, int* __restrict__ rowptr,
                        int* __restrict__ bsum, int n) {
    __shared__ int sdata[256];
    int t = threadIdx.x, b = blockIdx.x;
    int base = b * 1024 + t * 4;
    int v[4], s = 0;
#pragma unroll
    for (int k = 0; k < 4; ++k) { int i = base + k; v[k] = (i < n) ? cnt[i] : 0; s += v[k]; }
    sdata[t] = s;
    __syncthreads();
    int x = s;
    for (int off = 1; off < 256; off <<= 1) {
        int y = (t >= off) ? sdata[t - off] : 0;
        __syncthreads();
        x += y;
        sdata[t] = x;
        __syncthreads();
    }
    int run = x - s;
    if (t == 255) bsum[b] = x;
#pragma unroll
    for (int k = 0; k < 4; ++k) { int i = base + k; if (i < n) rowptr[i] = run; run += v[k]; }
}

__global__ void k_scan2(int* __restrict__ bsum, int nb) {
    __shared__ int sdata[256];
    int t = threadIdx.x;
    int s = (t < nb) ? bsum[t] : 0;
    sdata[t] = s;
    __syncthreads();
    int x = s;
    for (int off = 1; off < 256; off <<= 1) {
        int y = (t >= off) ? sdata[t - off] : 0;
        __syncthreads();
        x += y;
        sdata[t] = x;
        __syncthreads();
    }
    if (t < nb) bsum[t] = x - s;
}

__global__ void k_scan3(int* __restrict__ rowptr, const int* __restrict__ bsum, int n, int E) {
    int i = blockIdx.x * blockDim.x + threadIdx.x;
    if (i < n) rowptr[i] += bsum[i >> 10];
    else if (i == n) rowptr[n] = E;
}

// ---------------- reorder: NO atomics — pos = rowptr[dst] + rank ----------------

__global__ void k_reorder(const int* __restrict__ src, const int* __restrict__ dst,
                          const float* __restrict__ ew, const float* __restrict__ dinv,
                          const int* __restrict__ rowptr, const int* __restrict__ rank,
                          int2* __restrict__ edges, int nE) {
    int e = blockIdx.x * blockDim.x + threadIdx.x;
    if (e < nE) {
        int s = src[e];
        int d = dst[e];
        float w = dinv[s] * ew[e] * dinv[d];
        int pos = rowptr[d] + rank[e];
        edges[pos] = make_int2(s, __float_as_int(w));
    }
}

// ---------------- aggregate: out[n,:] = dinv[n]^2*h[n,:] + sum_e w_e * hb[src_e,:] ----
// one wave per node, lane = feature. Self term fp32; neighbor gathers bf16 (128 B/row).

__launch_bounds__(256)
__global__ void k_aggregate(const float* __restrict__ h, const unsigned short* __restrict__ hb,
                            const float* __restrict__ dinv,
                            const int2* __restrict__ edges, const int* __restrict__ rowptr,
                            float* __restrict__ out, int N) {
    int n = (blockIdx.x * 256 + threadIdx.x) >> 6;
    int lane = threadIdx.x & 63;
    if (n >= N) return;

    float dn = dinv[n];
    float acc = dn * dn * h[(size_t)n * HID + lane];

    int beg = rowptr[n], end = rowptr[n + 1];
    int j = beg;
    for (; j + 3 < end; j += 4) {
        int2 p0 = edges[j];
        int2 p1 = edges[j + 1];
        int2 p2 = edges[j + 2];
        int2 p3 = edges[j + 3];
        float h0 = bf2f(hb[(size_t)p0.x * HID + lane]);
        float h1 = bf2f(hb[(size_t)p1.x * HID + lane]);
        float h2 = bf2f(hb[(size_t)p2.x * HID + lane]);
        float h3 = bf2f(hb[(size_t)p3.x * HID + lane]);
        acc = fmaf(__int_as_float(p0.y), h0, acc);
        acc = fmaf(__int_as_float(p1.y), h1, acc);
        acc = fmaf(__int_as_float(p2.y), h2, acc);
        acc = fmaf(__int_as_float(p3.y), h3, acc);
    }
    for (; j < end; ++j) {
        int2 p = edges[j];
        acc = fmaf(__int_as_float(p.y), bf2f(hb[(size_t)p.x * HID + lane]), acc);
    }
    out[(size_t)n * HID + lane] = acc;
}

// ---------------- tiled GEMM: out[M,64] = act(A[M,K]) @ W[K,64]; also bf16 copy ----------------

template <int K_, bool RELU_BIAS>
__launch_bounds__(256)
__global__ void k_gemm_n64(const float* __restrict__ A, const float* __restrict__ W,
                           const float* __restrict__ bias, float* __restrict__ out,
                           unsigned short* __restrict__ outb, int M) {
    constexpr int BK = 16;
    __shared__ float As[BK][68];
    __shared__ float Ws[BK][64];

    const int t  = threadIdx.x;
    const int tx = t & 15;
    const int ty = t >> 4;
    const int row0 = blockIdx.x * 64;

    const int lr = t >> 2;
    const int lk = (t & 3) * 4;

    float acc[4][4] = {};

    for (int k0 = 0; k0 < K_; k0 += BK) {
        float4 av = make_float4(0.f, 0.f, 0.f, 0.f);
        int ar = row0 + lr;
        if (ar < M) {
            av = *(const float4*)&A[(long long)ar * K_ + k0 + lk];
            if (RELU_BIAS) {
                const float4 bv = *(const float4*)&bias[k0 + lk];
                av.x = fmaxf(av.x + bv.x, 0.f);
                av.y = fmaxf(av.y + bv.y, 0.f);
                av.z = fmaxf(av.z + bv.z, 0.f);
                av.w = fmaxf(av.w + bv.w, 0.f);
            }
        }
        As[lk + 0][lr] = av.x;
        As[lk + 1][lr] = av.y;
        As[lk + 2][lr] = av.z;
        As[lk + 3][lr] = av.w;

        *(float4*)&Ws[t >> 4][(t & 15) * 4] =
            *(const float4*)&W[(long long)(k0 + (t >> 4)) * 64 + (t & 15) * 4];

        __syncthreads();

#pragma unroll
        for (int kk = 0; kk < BK; ++kk) {
            float4 a4 = *(const float4*)&As[kk][ty * 4];
            float4 b4 = *(const float4*)&Ws[kk][tx * 4];
            float a[4] = {a4.x, a4.y, a4.z, a4.w};
            float b[4] = {b4.x, b4.y, b4.z, b4.w};
#pragma unroll
            for (int i = 0; i < 4; ++i)
#pragma unroll
                for (int j = 0; j < 4; ++j)
                    acc[i][j] = fmaf(a[i], b[j], acc[i][j]);
        }
        __syncthreads();
    }

#pragma unroll
    for (int i = 0; i < 4; ++i) {
        int r = row0 + ty * 4 + i;
        if (r < M) {
            *(float4*)&out[(long long)r * 64 + tx * 4] =
                make_float4(acc[i][0], acc[i][1], acc[i][2], acc[i][3]);
            ushort4 hv;
            hv.x = f2bf(acc[i][0]);
            hv.y = f2bf(acc[i][1]);
            hv.z = f2bf(acc[i][2]);
            hv.w = f2bf(acc[i][3]);
            *(ushort4*)&outb[(long long)r * 64 + tx * 4] = hv;
        }
    }
}

// ---------------- final: out[n,:5] = relu(agg[n,:]+b2) @ Wfc + bfc ----------------

__launch_bounds__(256)
__global__ void k_final(const float* __restrict__ agg, const float* __restrict__ b2,
                        const float* __restrict__ Wfc, const float* __restrict__ bfc,
                        float* __restrict__ out, int N) {
    __shared__ float Wsf[HID * OUT_DIM];
    __shared__ float bs[HID];
    int t = threadIdx.x;
    for (int i = t; i < HID * OUT_DIM; i += 256) Wsf[i] = Wfc[i];
    if (t < HID) bs[t] = b2[t];
    __syncthreads();

    int n = blockIdx.x * blockDim.x + t;
    if (n >= N) return;

    float acc[OUT_DIM];
#pragma unroll
    for (int o = 0; o < OUT_DIM; ++o) acc[o] = bfc[o];

    const float4* ag = (const float4*)&agg[(long long)n * HID];
#pragma unroll
    for (int k4 = 0; k4 < HID / 4; ++k4) {
        float4 v4 = ag[k4];
        float v[4] = {v4.x, v4.y, v4.z, v4.w};
#pragma unroll
        for (int j = 0; j < 4; ++j) {
            int k = k4 * 4 + j;
            float f = fmaxf(v[j] + bs[k], 0.f);
#pragma unroll
            for (int o = 0; o < OUT_DIM; ++o)
                acc[o] = fmaf(f, Wsf[k * OUT_DIM + o], acc[o]);
        }
    }
#pragma unroll
    for (int o = 0; o < OUT_DIM; ++o) out[(long long)n * OUT_DIM + o] = acc[o];
}

// ---------------- host launch ----------------

static inline size_t align_up(size_t x, size_t a) { return (x + a - 1) & ~(a - 1); }

extern "C" void kernel_launch(void* const* d_in, const int* in_sizes, int n_in,
                              void* d_out, int out_size, void* d_ws, size_t ws_size,
                              hipStream_t stream) {
    const float* x   = (const float*)d_in[0];
    const int*   ei  = (const int*)d_in[1];   // [2][E] int32
    const float* ew  = (const float*)d_in[2];
    const float* W1  = (const float*)d_in[3];
    const float* b1  = (const float*)d_in[4];
    const float* W2  = (const float*)d_in[5];
    const float* b2  = (const float*)d_in[6];
    const float* Wfc = (const float*)d_in[7];
    const float* bfc = (const float*)d_in[8];
    float* out = (float*)d_out;

    const int E = in_sizes[2];              // 3200000
    const int N = in_sizes[0] / IN_DIM;     // 100000
    const int* src = ei;
    const int* dst = ei + E;

    // workspace carve (hb aliases rank: rank is dead after k_reorder,
    // GEMM1 writes hb strictly after — same stream, sequential)
    char* p = (char*)d_ws;
    unsigned long long* packed = (unsigned long long*)p; p += align_up((size_t)N * 8, 256);
    float* dinv   = (float*)p;  p += align_up((size_t)N * 4, 256);
    int*   cnt    = (int*)p;    p += align_up((size_t)N * 4, 256);
    int*   rowptr = (int*)p;    p += align_up((size_t)(N + 1) * 4, 256);
    int*   bsum   = (int*)p;    p += align_up((size_t)256 * 4, 256);
    int*   rank   = (int*)p;    p += align_up((size_t)E * 4, 256);   // 12.8 MB
    unsigned short* hb = (unsigned short*)rank;                       // N*HID*2 = 12.8 MB
    int2*  edges  = (int2*)p;   p += align_up((size_t)E * 8, 256);
    float* bufA   = (float*)p;  p += align_up((size_t)N * HID * 4, 256);
    float* bufB   = (float*)p;  p += align_up((size_t)N * HID * 4, 256);
    (void)ws_size; (void)n_in; (void)out_size;

    const int BS = 256;
    dim3 blk(BS);
    int gN  = (N + BS - 1) / BS;
    int gN1 = (N + 1 + BS - 1) / BS;
    int gE  = (E + BS - 1) / BS;
    int gM  = (N + 63) / 64;
    int nb  = (N + 1023) / 1024;
    int gAg = (N + 3) / 4;

    // CSR build: 1 scattered atomic per edge total (proven round-3 path)
    k_init<<<gN, blk, 0, stream>>>(packed, N);
    k_hist<<<gE, blk, 0, stream>>>(dst, ew, packed, rank, E);
    k_dinv<<<gN, blk, 0, stream>>>(packed, dinv, cnt, N);
    k_scan1<<<nb, blk, 0, stream>>>(cnt, rowptr, bsum, N);
    k_scan2<<<1, blk, 0, stream>>>(bsum, nb);
    k_scan3<<<gN1, blk, 0, stream>>>(rowptr, bsum, N, E);
    k_reorder<<<gE, blk, 0, stream>>>(src, dst, ew, dinv, rowptr, rank, edges, E);

    // layer 1 (hb overwrites rank — rank dead from here on)
    k_gemm_n64<IN_DIM, false><<<gM, blk, 0, stream>>>(x, W1, nullptr, bufA, hb, N);
    k_aggregate<<<gAg, blk, 0, stream>>>(bufA, hb, dinv, edges, rowptr, bufB, N);

    // layer 2
    k_gemm_n64<HID, true><<<gM, blk, 0, stream>>>(bufB, W2, b1, bufA, hb, N);
    k_aggregate<<<gAg, blk, 0, stream>>>(bufA, hb, dinv, edges, rowptr, bufB, N);

    // final FC
    k_final<<<gN, blk, 0, stream>>>(bufB, b2, Wfc, bfc, out, N);
}